// Round 7
// baseline (381.221 us; speedup 1.0000x reference)
//
#include <hip/hip_runtime.h>
#include <math.h>

#define DEVFN __global__ __launch_bounds__(256)
#define DEVFN4 __global__ __launch_bounds__(256, 4)

namespace {
constexpr int LL  = 128;   // L
constexpr int MM2 = 255;   // 2L-1
constexpr int NT  = 256;   // ntheta
constexpr int NP  = 512;   // nphi
constexpr int NC  = 32;    // C_IN
constexpr int NO  = 32;    // C_OUT
constexpr float TWO_PI = 6.283185307179586476925286766559f;
}

typedef short v8s __attribute__((ext_vector_type(8)));   // 8 bf16 (4 VGPRs)
typedef float v4f __attribute__((ext_vector_type(4)));   // 4 fp32 acc

__device__ inline unsigned short f2bf(float f) {
  unsigned int u = __float_as_uint(f);
  return (unsigned short)((u + 0x7FFFu + ((u >> 16) & 1u)) >> 16);  // RNE
}

// ---------------------------------------------------------------- KP: prep (twiddles + x transpose)
DEVFN void kp_prep(const float* __restrict__ x, unsigned short* __restrict__ tw1t,
                   unsigned short* __restrict__ vt, unsigned short* __restrict__ xb) {
  __shared__ float sm[32][65];
  const int bid = blockIdx.x;
  const int tid = threadIdx.x;
  const float phi = TWO_PI / (float)NP;
  if (bid < 512) {
    const int idx = bid * 256 + tid;  // 0..131071
    const float fs = TWO_PI / (float)NP;
    {
      const int n = idx >> 9, p = idx & 511;
      const int m = n >> 1;
      const int k = (m * p) & (NP - 1);
      float s, c;
      sincosf(phi * (float)k, &s, &c);
      tw1t[idx] = f2bf((n & 1) ? (-s * fs) : (c * fs));
    }
    {
      const int p = idx >> 8, k = idx & 255;
      const int m = k >> 1;
      const int kk = (m * p) & (NP - 1);
      float s, c;
      sincosf(phi * (float)kk, &s, &c);
      vt[idx] = f2bf((k & 1) ? s : c);
    }
  } else {
    const int q = bid - 512;           // 0..2047
    const int t = q >> 3;
    const int p0 = (q & 7) * 64;
#pragma unroll
    for (int i = 0; i < 8; ++i) {
      const int idx = tid + i * 256;
      const int p = idx >> 5, c = idx & 31;
      sm[c][p] = x[((size_t)t * NP + p0 + p) * NC + c];
    }
    __syncthreads();
    const int c = tid >> 3, pg = tid & 7;
    unsigned short pk[8];
#pragma unroll
    for (int u = 0; u < 8; ++u) pk[u] = f2bf(sm[c][pg * 8 + u]);
    *(uint4*)(xb + ((size_t)(t * 32 + c)) * NP + p0 + pg * 8) = *(const uint4*)pk;
  }
}

// ---------------------------------------------------------------- K1: forward DFT via MFMA  (R3 proven tile)
// C[r][n] = sum_p Xb[r][p] * tw1t[n][p];  fw{r,i}[m][t][c] = C * wg[t]
// M=8192, N=256, K=512.  BM=128 x BN=64 -> grid (64,4) = 256 blocks.
DEVFN void k1_mfma(const unsigned short* __restrict__ xb,
                   const unsigned short* __restrict__ tw1t,
                   const float* __restrict__ wg,
                   float* __restrict__ fwr, float* __restrict__ fwi) {
  __shared__ unsigned short As[128 * 32];
  __shared__ unsigned short Bs[64 * 32];
  const int tid = threadIdx.x;
  const int r0 = blockIdx.x * 128;
  const int n0 = blockIdx.y * 64;
  const int wid = tid >> 6, lane = tid & 63;
  const int wm = wid & 1, wn = wid >> 1;   // 2x2 waves, wave tile 64(M) x 32(N)
  v4f acc[4][2];
#pragma unroll
  for (int i = 0; i < 4; ++i)
#pragma unroll
    for (int j = 0; j < 2; ++j) {
      acc[i][j][0] = 0.f; acc[i][j][1] = 0.f; acc[i][j][2] = 0.f; acc[i][j][3] = 0.f;
    }
  const int lr = lane & 15, lk = (lane >> 4) * 8;
  for (int k0 = 0; k0 < 512; k0 += 32) {
#pragma unroll
    for (int s = 0; s < 3; ++s) {
      const int chunk = tid + s * 256;      // 768 chunks x 16B (A:512, B:256)
      if (chunk < 512) {
        const int row = chunk >> 2, c16 = chunk & 3;
        *(uint4*)&As[row * 32 + c16 * 8] =
            *(const uint4*)&xb[(size_t)(r0 + row) * 512 + k0 + c16 * 8];
      } else {
        const int bc = chunk - 512;
        const int row = bc >> 2, c16 = bc & 3;
        *(uint4*)&Bs[row * 32 + c16 * 8] =
            *(const uint4*)&tw1t[(size_t)(n0 + row) * 512 + k0 + c16 * 8];
      }
    }
    __syncthreads();
    v8s af[4], bf[2];
#pragma unroll
    for (int i = 0; i < 4; ++i) af[i] = *(const v8s*)&As[(wm * 64 + i * 16 + lr) * 32 + lk];
#pragma unroll
    for (int j = 0; j < 2; ++j) bf[j] = *(const v8s*)&Bs[(wn * 32 + j * 16 + lr) * 32 + lk];
#pragma unroll
    for (int i = 0; i < 4; ++i)
#pragma unroll
      for (int j = 0; j < 2; ++j)
        acc[i][j] = __builtin_amdgcn_mfma_f32_16x16x32_bf16(af[i], bf[j], acc[i][j], 0, 0, 0);
    __syncthreads();
  }
  const int lrow = (lane >> 4) * 4;
#pragma unroll
  for (int i = 0; i < 4; ++i) {
    const int rbase = r0 + wm * 64 + i * 16 + lrow;
    const int t = rbase >> 5, c0 = rbase & 31;
    const float w = wg[t];
#pragma unroll
    for (int j = 0; j < 2; ++j) {
      const int n = n0 + wn * 32 + j * 16 + lr;
      const int mI = n >> 1;
      float* dst = (n & 1) ? fwi : fwr;
      float4 v = {acc[i][j][0] * w, acc[i][j][1] * w, acc[i][j][2] * w, acc[i][j][3] * w};
      *(float4*)&dst[((size_t)mI * NT + t) * NC + c0] = v;
    }
  }
}

// ---------------------------------------------------------------- K2: flm (l >= m), 4 l per wave (R6)
DEVFN4 void k2_flm(const float* __restrict__ leg, const float* __restrict__ fwr,
                   const float* __restrict__ fwi, float* __restrict__ flr,
                   float* __restrict__ fli) {
  const int m = blockIdx.x;
  const int wid = threadIdx.x >> 6, lane = threadIdx.x & 63;
  const int lb = m + blockIdx.y * 16 + wid * 4;   // wave owns lb..lb+3
  if (lb >= LL) return;                           // no barriers below
  const int c = lane & 31;
  const float* fp = ((lane >> 5) ? fwi : fwr) + (size_t)m * NT * NC + c;
  const float* lg[4];
#pragma unroll
  for (int i = 0; i < 4; ++i) {
    const int l = min(lb + i, LL - 1);
    lg[i] = leg + ((size_t)(l * MM2 + 127 + m)) * NT;
  }
  float a[4] = {};
#pragma unroll 2
  for (int t = 0; t < NT; t += 4) {
    const float f0 = fp[(t + 0) * NC];
    const float f1 = fp[(t + 1) * NC];
    const float f2 = fp[(t + 2) * NC];
    const float f3 = fp[(t + 3) * NC];
#pragma unroll
    for (int i = 0; i < 4; ++i) {
      const float4 b = *(const float4*)(lg[i] + t);
      a[i] = fmaf(b.x, f0, a[i]);
      a[i] = fmaf(b.y, f1, a[i]);
      a[i] = fmaf(b.z, f2, a[i]);
      a[i] = fmaf(b.w, f3, a[i]);
    }
  }
  float* outp = (lane >> 5) ? fli : flr;
#pragma unroll
  for (int i = 0; i < 4; ++i)
    if (lb + i < LL) outp[(size_t)(m * LL + lb + i) * NC + c] = a[i];
}

// ---------------------------------------------------------------- K3: channel mix, wave per (m,l) (R6)
// Pure weight stream (132 MB read once), 16 float4 loads upfront.
DEVFN4 void k3_mix(const float* __restrict__ flr, const float* __restrict__ fli,
                   const float* __restrict__ wr, const float* __restrict__ wi,
                   float* __restrict__ ya, float* __restrict__ yb) {
  const int m = blockIdx.x;
  const int wid = threadIdx.x >> 6, lane = threadIdx.x & 63;
  const int l = m + blockIdx.y * 4 + wid;
  if (l >= LL) return;
  const int c8 = lane >> 3;          // c-group: c = c8*4 + i
  const int o8 = lane & 7;           // o-quad:  o = o8*4 ..+3
  const int c0 = c8 * 4, o0 = o8 * 4;
  const float s0 = (m > 0) ? 1.0f : 0.0f;
  const size_t rp = ((size_t)(l * MM2 + 127 + m) * NC) * NO;
  const size_t rn = ((size_t)(l * MM2 + 127 - m) * NC) * NO;
  float4 Wrp[4], Wrn[4], Wip[4], Win[4];
#pragma unroll
  for (int i = 0; i < 4; ++i) {
    const size_t co = (size_t)(c0 + i) * NO + o0;
    Wrp[i] = *(const float4*)&wr[rp + co];
    Wrn[i] = *(const float4*)&wr[rn + co];
    Wip[i] = *(const float4*)&wi[rp + co];
    Win[i] = *(const float4*)&wi[rn + co];
  }
  const float4 fa4 = *(const float4*)&flr[(size_t)(m * LL + l) * NC + c0];
  const float4 fb4 = *(const float4*)&fli[(size_t)(m * LL + l) * NC + c0];
  float4 accA = {0.f, 0.f, 0.f, 0.f}, accB = {0.f, 0.f, 0.f, 0.f};
#pragma unroll
  for (int i = 0; i < 4; ++i) {
    const float fa = (i == 0) ? fa4.x : (i == 1) ? fa4.y : (i == 2) ? fa4.z : fa4.w;
    const float fb = (i == 0) ? fb4.x : (i == 1) ? fb4.y : (i == 2) ? fb4.z : fb4.w;
    float4 wa, wb;
    wa.x = fmaf(s0, Wrn[i].x, Wrp[i].x); wa.y = fmaf(s0, Wrn[i].y, Wrp[i].y);
    wa.z = fmaf(s0, Wrn[i].z, Wrp[i].z); wa.w = fmaf(s0, Wrn[i].w, Wrp[i].w);
    wb.x = fmaf(s0, Win[i].x, -Wip[i].x); wb.y = fmaf(s0, Win[i].y, -Wip[i].y);
    wb.z = fmaf(s0, Win[i].z, -Wip[i].z); wb.w = fmaf(s0, Win[i].w, -Wip[i].w);
    accA.x = fmaf(fa, wa.x, fmaf(fb, wb.x, accA.x));
    accA.y = fmaf(fa, wa.y, fmaf(fb, wb.y, accA.y));
    accA.z = fmaf(fa, wa.z, fmaf(fb, wb.z, accA.z));
    accA.w = fmaf(fa, wa.w, fmaf(fb, wb.w, accA.w));
    accB.x = fmaf(fa, wb.x, fmaf(-fb, wa.x, accB.x));
    accB.y = fmaf(fa, wb.y, fmaf(-fb, wa.y, accB.y));
    accB.z = fmaf(fa, wb.z, fmaf(-fb, wa.z, accB.z));
    accB.w = fmaf(fa, wb.w, fmaf(-fb, wa.w, accB.w));
  }
#pragma unroll
  for (int mask = 8; mask <= 32; mask <<= 1) {
    accA.x += __shfl_xor(accA.x, mask); accA.y += __shfl_xor(accA.y, mask);
    accA.z += __shfl_xor(accA.z, mask); accA.w += __shfl_xor(accA.w, mask);
    accB.x += __shfl_xor(accB.x, mask); accB.y += __shfl_xor(accB.y, mask);
    accB.z += __shfl_xor(accB.z, mask); accB.w += __shfl_xor(accB.w, mask);
  }
  if (c8 == 0) {
    *(float4*)&ya[(size_t)(m * LL + l) * NO + o0] = accA;
    *(float4*)&yb[(size_t)(m * LL + l) * NO + o0] = accB;
  }
}

// ---------------------------------------------------------------- K4: inverse Legendre -> Ut bf16 (R6)
DEVFN4 void k4_G(const float* __restrict__ leg, const float* __restrict__ ya,
                 const float* __restrict__ yb, unsigned short* __restrict__ ut) {
  const int m = blockIdx.x;
  const int tc = blockIdx.y;
  const int o = threadIdx.x & 31;
  const int tq = threadIdx.x >> 5;
  const int t0 = tc * 32 + tq * 4;
  float aa[4] = {}, bb[4] = {};
#pragma unroll 8
  for (int l = m; l < LL; ++l) {
    const float4 g = *(const float4*)(leg + ((size_t)(l * MM2 + 127 + m)) * NT + t0);
    const float yav = ya[(m * LL + l) * NO + o];
    const float ybv = yb[(m * LL + l) * NO + o];
    aa[0] = fmaf(g.x, yav, aa[0]);  bb[0] = fmaf(g.x, ybv, bb[0]);
    aa[1] = fmaf(g.y, yav, aa[1]);  bb[1] = fmaf(g.y, ybv, bb[1]);
    aa[2] = fmaf(g.z, yav, aa[2]);  bb[2] = fmaf(g.z, ybv, bb[2]);
    aa[3] = fmaf(g.w, yav, aa[3]);  bb[3] = fmaf(g.w, ybv, bb[3]);
  }
#pragma unroll
  for (int i = 0; i < 4; ++i) {
    const unsigned int pk = (unsigned int)f2bf(aa[i]) | ((unsigned int)f2bf(bb[i]) << 16);
    *(unsigned int*)&ut[((size_t)((t0 + i) * 32 + o)) * 256 + 2 * m] = pk;
  }
}

// ---------------------------------------------------------------- K5: inverse DFT via MFMA (R3 proven tile)
// D[p][r] = sum_k vt[p][k] * ut[r][k];  out[o][t][p] = D,  r=t*32+o   (M=512,N=8192,K=256)
DEVFN void k5_mfma(const unsigned short* __restrict__ ut,
                   const unsigned short* __restrict__ vt,
                   float* __restrict__ out) {
  __shared__ unsigned short As[128 * 32];  // vt tile (p rows)
  __shared__ unsigned short Bs[128 * 32];  // ut tile (r rows)
  const int tid = threadIdx.x;
  const int p0 = blockIdx.x * 128;
  const int r0 = blockIdx.y * 128;
  const int wid = tid >> 6, lane = tid & 63;
  const int wm = wid & 1, wn = wid >> 1;
  v4f acc[4][4];
#pragma unroll
  for (int i = 0; i < 4; ++i)
#pragma unroll
    for (int j = 0; j < 4; ++j) {
      acc[i][j][0] = 0.f; acc[i][j][1] = 0.f; acc[i][j][2] = 0.f; acc[i][j][3] = 0.f;
    }
  const int lr = lane & 15, lk = (lane >> 4) * 8;
  for (int k0 = 0; k0 < 256; k0 += 32) {
#pragma unroll
    for (int s = 0; s < 2; ++s) {
      const int chunk = tid + s * 256;
      const int row = chunk >> 2, c16 = chunk & 3;
      *(uint4*)&As[row * 32 + c16 * 8] =
          *(const uint4*)&vt[(size_t)(p0 + row) * 256 + k0 + c16 * 8];
      *(uint4*)&Bs[row * 32 + c16 * 8] =
          *(const uint4*)&ut[(size_t)(r0 + row) * 256 + k0 + c16 * 8];
    }
    __syncthreads();
    v8s af[4], bf[4];
#pragma unroll
    for (int i = 0; i < 4; ++i) af[i] = *(const v8s*)&As[(wm * 64 + i * 16 + lr) * 32 + lk];
#pragma unroll
    for (int j = 0; j < 4; ++j) bf[j] = *(const v8s*)&Bs[(wn * 64 + j * 16 + lr) * 32 + lk];
#pragma unroll
    for (int i = 0; i < 4; ++i)
#pragma unroll
      for (int j = 0; j < 4; ++j)
        acc[i][j] = __builtin_amdgcn_mfma_f32_16x16x32_bf16(af[i], bf[j], acc[i][j], 0, 0, 0);
    __syncthreads();
  }
  const int lrow = (lane >> 4) * 4;
#pragma unroll
  for (int i = 0; i < 4; ++i) {
    const int pbase = p0 + wm * 64 + i * 16 + lrow;
#pragma unroll
    for (int j = 0; j < 4; ++j) {
      const int r = r0 + wn * 64 + j * 16 + lr;
      const int t = r >> 5, o = r & 31;
      float4 v = {acc[i][j][0], acc[i][j][1], acc[i][j][2], acc[i][j][3]};
      *(float4*)&out[((size_t)o * NT + t) * NP + pbase] = v;
    }
  }
}

// ---------------------------------------------------------------- launch
extern "C" void kernel_launch(void* const* d_in, const int* in_sizes, int n_in,
                              void* d_out, int out_size, void* d_ws, size_t ws_size,
                              hipStream_t stream) {
  const float* x   = (const float*)d_in[0];
  const float* wr  = (const float*)d_in[1];
  const float* wi  = (const float*)d_in[2];
  const float* leg = (const float*)d_in[3];
  const float* wg  = (const float*)d_in[4];
  float* out = (float*)d_out;

  unsigned short* tw1t = (unsigned short*)d_ws;     // 256*512   = 131072
  unsigned short* vt   = tw1t + 131072;             // 512*256   = 131072
  unsigned short* xb   = vt + 131072;               // 8192*512  = 4194304
  unsigned short* ut   = xb + 4194304;              // 8192*256  = 2097152
  float* fwr = (float*)(ut + 2097152);              // 128*256*32 = 1048576
  float* fwi = fwr + 1048576;
  float* flr = fwi + 1048576;                       // 128*128*32 = 524288
  float* fli = flr + 524288;
  float* ya  = fli + 524288;
  float* yb  = ya + 524288;                         // total ~26 MB

  hipLaunchKernelGGL(kp_prep, dim3(2560), dim3(256), 0, stream, x, tw1t, vt, xb);
  hipLaunchKernelGGL(k1_mfma, dim3(64, 4), dim3(256), 0, stream, xb, tw1t, wg, fwr, fwi);
  hipLaunchKernelGGL(k2_flm, dim3(128, 8), dim3(256), 0, stream, leg, fwr, fwi, flr, fli);
  hipLaunchKernelGGL(k3_mix, dim3(128, 32), dim3(256), 0, stream, flr, fli, wr, wi, ya, yb);
  hipLaunchKernelGGL(k4_G, dim3(128, 8), dim3(256), 0, stream, leg, ya, yb, ut);
  hipLaunchKernelGGL(k5_mfma, dim3(4, 64), dim3(256), 0, stream, ut, vt, out);
}

// Round 8
// 380.396 us; speedup vs baseline: 1.0022x; 1.0022x over previous
//
#include <hip/hip_runtime.h>
#include <math.h>

#define DEVFN __global__ __launch_bounds__(256)

namespace {
constexpr int LL  = 128;   // L
constexpr int MM2 = 255;   // 2L-1
constexpr int NT  = 256;   // ntheta
constexpr int NP  = 512;   // nphi
constexpr int NC  = 32;    // C_IN
constexpr int NO  = 32;    // C_OUT
constexpr float TWO_PI = 6.283185307179586476925286766559f;
}

typedef short v8s __attribute__((ext_vector_type(8)));   // 8 bf16 (4 VGPRs)
typedef float v4f __attribute__((ext_vector_type(4)));   // 4 fp32 acc

__device__ inline unsigned short f2bf(float f) {
  unsigned int u = __float_as_uint(f);
  return (unsigned short)((u + 0x7FFFu + ((u >> 16) & 1u)) >> 16);  // RNE
}

// ---------------------------------------------------------------- KP: prep (twiddles + x transpose)
DEVFN void kp_prep(const float* __restrict__ x, unsigned short* __restrict__ tw1t,
                   unsigned short* __restrict__ vt, unsigned short* __restrict__ xb) {
  __shared__ float sm[32][65];
  const int bid = blockIdx.x;
  const int tid = threadIdx.x;
  const float phi = TWO_PI / (float)NP;
  if (bid < 512) {
    const int idx = bid * 256 + tid;  // 0..131071
    const float fs = TWO_PI / (float)NP;
    {
      const int n = idx >> 9, p = idx & 511;
      const int m = n >> 1;
      const int k = (m * p) & (NP - 1);
      float s, c;
      sincosf(phi * (float)k, &s, &c);
      tw1t[idx] = f2bf((n & 1) ? (-s * fs) : (c * fs));
    }
    {
      const int p = idx >> 8, k = idx & 255;
      const int m = k >> 1;
      const int kk = (m * p) & (NP - 1);
      float s, c;
      sincosf(phi * (float)kk, &s, &c);
      vt[idx] = f2bf((k & 1) ? s : c);
    }
  } else {
    const int q = bid - 512;           // 0..2047
    const int t = q >> 3;
    const int p0 = (q & 7) * 64;
#pragma unroll
    for (int i = 0; i < 8; ++i) {
      const int idx = tid + i * 256;
      const int p = idx >> 5, c = idx & 31;
      sm[c][p] = x[((size_t)t * NP + p0 + p) * NC + c];
    }
    __syncthreads();
    const int c = tid >> 3, pg = tid & 7;
    unsigned short pk[8];
#pragma unroll
    for (int u = 0; u < 8; ++u) pk[u] = f2bf(sm[c][pg * 8 + u]);
    *(uint4*)(xb + ((size_t)(t * 32 + c)) * NP + p0 + pg * 8) = *(const uint4*)pk;
  }
}

// ---------------------------------------------------------------- K1: forward DFT via MFMA (R3 proven)
// M=8192, N=256, K=512.  BM=128 x BN=64 -> grid (64,4) = 256 blocks.
DEVFN void k1_mfma(const unsigned short* __restrict__ xb,
                   const unsigned short* __restrict__ tw1t,
                   const float* __restrict__ wg,
                   float* __restrict__ fwr, float* __restrict__ fwi) {
  __shared__ unsigned short As[128 * 32];
  __shared__ unsigned short Bs[64 * 32];
  const int tid = threadIdx.x;
  const int r0 = blockIdx.x * 128;
  const int n0 = blockIdx.y * 64;
  const int wid = tid >> 6, lane = tid & 63;
  const int wm = wid & 1, wn = wid >> 1;   // 2x2 waves, wave tile 64(M) x 32(N)
  v4f acc[4][2];
#pragma unroll
  for (int i = 0; i < 4; ++i)
#pragma unroll
    for (int j = 0; j < 2; ++j) {
      acc[i][j][0] = 0.f; acc[i][j][1] = 0.f; acc[i][j][2] = 0.f; acc[i][j][3] = 0.f;
    }
  const int lr = lane & 15, lk = (lane >> 4) * 8;
  for (int k0 = 0; k0 < 512; k0 += 32) {
#pragma unroll
    for (int s = 0; s < 3; ++s) {
      const int chunk = tid + s * 256;      // 768 chunks x 16B (A:512, B:256)
      if (chunk < 512) {
        const int row = chunk >> 2, c16 = chunk & 3;
        *(uint4*)&As[row * 32 + c16 * 8] =
            *(const uint4*)&xb[(size_t)(r0 + row) * 512 + k0 + c16 * 8];
      } else {
        const int bc = chunk - 512;
        const int row = bc >> 2, c16 = bc & 3;
        *(uint4*)&Bs[row * 32 + c16 * 8] =
            *(const uint4*)&tw1t[(size_t)(n0 + row) * 512 + k0 + c16 * 8];
      }
    }
    __syncthreads();
    v8s af[4], bf[2];
#pragma unroll
    for (int i = 0; i < 4; ++i) af[i] = *(const v8s*)&As[(wm * 64 + i * 16 + lr) * 32 + lk];
#pragma unroll
    for (int j = 0; j < 2; ++j) bf[j] = *(const v8s*)&Bs[(wn * 32 + j * 16 + lr) * 32 + lk];
#pragma unroll
    for (int i = 0; i < 4; ++i)
#pragma unroll
      for (int j = 0; j < 2; ++j)
        acc[i][j] = __builtin_amdgcn_mfma_f32_16x16x32_bf16(af[i], bf[j], acc[i][j], 0, 0, 0);
    __syncthreads();
  }
  const int lrow = (lane >> 4) * 4;
#pragma unroll
  for (int i = 0; i < 4; ++i) {
    const int rbase = r0 + wm * 64 + i * 16 + lrow;
    const int t = rbase >> 5, c0 = rbase & 31;
    const float w = wg[t];
#pragma unroll
    for (int j = 0; j < 2; ++j) {
      const int n = n0 + wn * 32 + j * 16 + lr;
      const int mI = n >> 1;
      float* dst = (n & 1) ? fwi : fwr;
      float4 v = {acc[i][j][0] * w, acc[i][j][1] * w, acc[i][j][2] * w, acc[i][j][3] * w};
      *(float4*)&dst[((size_t)mI * NT + t) * NC + c0] = v;
    }
  }
}

// ---------------------------------------------------------------- K2: flm, t-SPLIT across waves
// Block = (m, 4 consecutive l).  Wave w computes the t-quarter [64w,64w+64)
// for ALL 4 l (fw reuse x4); LDS combine.  Serial chain per wave: 16 steps
// (was 64) -> tail-latency cut ~4x.
DEVFN void k2_flm(const float* __restrict__ leg, const float* __restrict__ fwr,
                  const float* __restrict__ fwi, float* __restrict__ flr,
                  float* __restrict__ fli) {
  __shared__ float sp[4][4][64];   // [wave][l-idx][lane]
  const int m = blockIdx.x;
  const int lb = m + blockIdx.y * 4;
  if (lb >= LL) return;            // uniform: whole block exits
  const int wid = threadIdx.x >> 6, lane = threadIdx.x & 63;
  const int c = lane & 31;
  const float* fp = ((lane >> 5) ? fwi : fwr) + (size_t)m * NT * NC + c;
  const float* lg[4];
#pragma unroll
  for (int i = 0; i < 4; ++i) {
    const int l = min(lb + i, LL - 1);
    lg[i] = leg + ((size_t)(l * MM2 + 127 + m)) * NT;
  }
  float a[4] = {};
  const int tbeg = wid * 64;
#pragma unroll 2
  for (int tt = 0; tt < 64; tt += 4) {
    const int t = tbeg + tt;
    const float f0 = fp[(t + 0) * NC];
    const float f1 = fp[(t + 1) * NC];
    const float f2 = fp[(t + 2) * NC];
    const float f3 = fp[(t + 3) * NC];
#pragma unroll
    for (int i = 0; i < 4; ++i) {
      const float4 b = *(const float4*)(lg[i] + t);
      a[i] = fmaf(b.x, f0, a[i]);
      a[i] = fmaf(b.y, f1, a[i]);
      a[i] = fmaf(b.z, f2, a[i]);
      a[i] = fmaf(b.w, f3, a[i]);
    }
  }
#pragma unroll
  for (int i = 0; i < 4; ++i) sp[wid][i][lane] = a[i];
  __syncthreads();
  const int l = lb + wid;          // wave wid finalizes l-idx wid
  if (l < LL) {
    const float tot = ((sp[0][wid][lane] + sp[1][wid][lane]) +
                       sp[2][wid][lane]) + sp[3][wid][lane];   // t-order
    float* outp = (lane >> 5) ? fli : flr;
    outp[(size_t)(m * LL + l) * NC + c] = tot;
  }
}

// ---------------------------------------------------------------- K3: channel mix, wave per (m,l) (R3 proven)
DEVFN void k3_mix(const float* __restrict__ flr, const float* __restrict__ fli,
                  const float* __restrict__ wr, const float* __restrict__ wi,
                  float* __restrict__ ya, float* __restrict__ yb) {
  const int m  = blockIdx.x;
  const int wid = threadIdx.x >> 6, lane = threadIdx.x & 63;
  const int l = m + blockIdx.y * 4 + wid;
  if (l >= LL) return;
  const int c8 = lane >> 3;          // c-group: c = c8*4 + i
  const int o8 = lane & 7;           // o-quad:  o = o8*4 ..+3
  const int c0 = c8 * 4, o0 = o8 * 4;
  const float s0 = (m > 0) ? 1.0f : 0.0f;
  const size_t rp = ((size_t)(l * MM2 + 127 + m) * NC) * NO;
  const size_t rn = ((size_t)(l * MM2 + 127 - m) * NC) * NO;
  const float4 fa4 = *(const float4*)&flr[(size_t)(m * LL + l) * NC + c0];
  const float4 fb4 = *(const float4*)&fli[(size_t)(m * LL + l) * NC + c0];
  float4 accA = {0.f, 0.f, 0.f, 0.f}, accB = {0.f, 0.f, 0.f, 0.f};
#pragma unroll
  for (int i = 0; i < 4; ++i) {
    const int c = c0 + i;
    const float4 wrp = *(const float4*)&wr[rp + (size_t)c * NO + o0];
    const float4 wrn = *(const float4*)&wr[rn + (size_t)c * NO + o0];
    const float4 wip = *(const float4*)&wi[rp + (size_t)c * NO + o0];
    const float4 win = *(const float4*)&wi[rn + (size_t)c * NO + o0];
    const float fa = (i == 0) ? fa4.x : (i == 1) ? fa4.y : (i == 2) ? fa4.z : fa4.w;
    const float fb = (i == 0) ? fb4.x : (i == 1) ? fb4.y : (i == 2) ? fb4.z : fb4.w;
    float4 wa, wb;
    wa.x = fmaf(s0, wrn.x, wrp.x); wa.y = fmaf(s0, wrn.y, wrp.y);
    wa.z = fmaf(s0, wrn.z, wrp.z); wa.w = fmaf(s0, wrn.w, wrp.w);
    wb.x = fmaf(s0, win.x, -wip.x); wb.y = fmaf(s0, win.y, -wip.y);
    wb.z = fmaf(s0, win.z, -wip.z); wb.w = fmaf(s0, win.w, -wip.w);
    accA.x = fmaf(fa, wa.x, fmaf(fb, wb.x, accA.x));
    accA.y = fmaf(fa, wa.y, fmaf(fb, wb.y, accA.y));
    accA.z = fmaf(fa, wa.z, fmaf(fb, wb.z, accA.z));
    accA.w = fmaf(fa, wa.w, fmaf(fb, wb.w, accA.w));
    accB.x = fmaf(fa, wb.x, fmaf(-fb, wa.x, accB.x));
    accB.y = fmaf(fa, wb.y, fmaf(-fb, wa.y, accB.y));
    accB.z = fmaf(fa, wb.z, fmaf(-fb, wa.z, accB.z));
    accB.w = fmaf(fa, wb.w, fmaf(-fb, wa.w, accB.w));
  }
#pragma unroll
  for (int mask = 8; mask <= 32; mask <<= 1) {
    accA.x += __shfl_xor(accA.x, mask); accA.y += __shfl_xor(accA.y, mask);
    accA.z += __shfl_xor(accA.z, mask); accA.w += __shfl_xor(accA.w, mask);
    accB.x += __shfl_xor(accB.x, mask); accB.y += __shfl_xor(accB.y, mask);
    accB.z += __shfl_xor(accB.z, mask); accB.w += __shfl_xor(accB.w, mask);
  }
  if (c8 == 0) {
    *(float4*)&ya[(size_t)(m * LL + l) * NO + o0] = accA;
    *(float4*)&yb[(size_t)(m * LL + l) * NO + o0] = accB;
  }
}

// ---------------------------------------------------------------- K4: partial inverse Legendre (l-SPLIT)
// Block = (m, tc, lq): sums l in [max(m,32*lq), 32*(lq+1)) for t-chunk tc.
// Serial chain <= 32 iters (was <=128).  fp32 partials to gp[lq][k][r];
// every slice written every iteration (zeros when empty).
DEVFN void k4_G(const float* __restrict__ leg, const float* __restrict__ ya,
                const float* __restrict__ yb, float* __restrict__ gp) {
  const int m  = blockIdx.x;
  const int tc = blockIdx.y & 7;
  const int lq = blockIdx.y >> 3;
  const int o  = threadIdx.x & 31;
  const int tq = threadIdx.x >> 5;
  const int t0 = tc * 32 + tq * 4;
  const int lstart = max(m, lq * 32);
  const int lend   = (lq + 1) * 32;
  float aa[4] = {}, bb[4] = {};
  for (int l = lstart; l < lend; ++l) {
    const float4 g = *(const float4*)(leg + ((size_t)(l * MM2 + 127 + m)) * NT + t0);
    const float yav = ya[(m * LL + l) * NO + o];
    const float ybv = yb[(m * LL + l) * NO + o];
    aa[0] = fmaf(g.x, yav, aa[0]);  bb[0] = fmaf(g.x, ybv, bb[0]);
    aa[1] = fmaf(g.y, yav, aa[1]);  bb[1] = fmaf(g.y, ybv, bb[1]);
    aa[2] = fmaf(g.z, yav, aa[2]);  bb[2] = fmaf(g.z, ybv, bb[2]);
    aa[3] = fmaf(g.w, yav, aa[3]);  bb[3] = fmaf(g.w, ybv, bb[3]);
  }
  float* gq = gp + (size_t)lq * (256 * 8192);
#pragma unroll
  for (int i = 0; i < 4; ++i) {
    const size_t rr = (size_t)(t0 + i) * 32 + o;
    gq[(size_t)(2 * m) * 8192 + rr] = aa[i];
    gq[(size_t)(2 * m + 1) * 8192 + rr] = bb[i];
  }
}

// ---------------------------------------------------------------- K5: inverse DFT via MFMA (R3 tile + gp gather)
// D[p][r] = sum_k vt[p][k] * ut[r][k];  ut[r][k] = sum_lq gp[lq][k][r]
// (fp32 sum -> bf16 during staging).  BM=128 x BN=128, grid (4,64).
DEVFN void k5_mfma(const float* __restrict__ gp,
                   const unsigned short* __restrict__ vt,
                   float* __restrict__ out) {
  __shared__ unsigned short As[128 * 32];  // vt tile (p rows)
  __shared__ unsigned short Bs[128 * 32];  // summed ut tile (r rows)
  const int tid = threadIdx.x;
  const int p0 = blockIdx.x * 128;
  const int r0 = blockIdx.y * 128;
  const int wid = tid >> 6, lane = tid & 63;
  const int wm = wid & 1, wn = wid >> 1;
  v4f acc[4][4];
#pragma unroll
  for (int i = 0; i < 4; ++i)
#pragma unroll
    for (int j = 0; j < 4; ++j) {
      acc[i][j][0] = 0.f; acc[i][j][1] = 0.f; acc[i][j][2] = 0.f; acc[i][j][3] = 0.f;
    }
  const int lr = lane & 15, lk = (lane >> 4) * 8;
  const int ke = tid >> 3, rq = tid & 7;   // gather: k = k0+ke, rows rq*16..+15
  constexpr size_t Q = (size_t)256 * 8192;
  for (int k0 = 0; k0 < 256; k0 += 32) {
#pragma unroll
    for (int s = 0; s < 2; ++s) {
      const int chunk = tid + s * 256;     // A: 512 chunks x 16B
      const int row = chunk >> 2, c16 = chunk & 3;
      *(uint4*)&As[row * 32 + c16 * 8] =
          *(const uint4*)&vt[(size_t)(p0 + row) * 256 + k0 + c16 * 8];
    }
#pragma unroll
    for (int j4 = 0; j4 < 4; ++j4) {
      const size_t base = (size_t)(k0 + ke) * 8192 + r0 + rq * 16 + j4 * 4;
      float4 s0 = *(const float4*)&gp[base];
      const float4 a1 = *(const float4*)&gp[base + Q];
      const float4 a2 = *(const float4*)&gp[base + 2 * Q];
      const float4 a3 = *(const float4*)&gp[base + 3 * Q];
      s0.x = ((s0.x + a1.x) + a2.x) + a3.x;
      s0.y = ((s0.y + a1.y) + a2.y) + a3.y;
      s0.z = ((s0.z + a1.z) + a2.z) + a3.z;
      s0.w = ((s0.w + a1.w) + a2.w) + a3.w;
      const int rbase = rq * 16 + j4 * 4;
      Bs[(rbase + 0) * 32 + ke] = f2bf(s0.x);
      Bs[(rbase + 1) * 32 + ke] = f2bf(s0.y);
      Bs[(rbase + 2) * 32 + ke] = f2bf(s0.z);
      Bs[(rbase + 3) * 32 + ke] = f2bf(s0.w);
    }
    __syncthreads();
    v8s af[4], bf[4];
#pragma unroll
    for (int i = 0; i < 4; ++i) af[i] = *(const v8s*)&As[(wm * 64 + i * 16 + lr) * 32 + lk];
#pragma unroll
    for (int j = 0; j < 4; ++j) bf[j] = *(const v8s*)&Bs[(wn * 64 + j * 16 + lr) * 32 + lk];
#pragma unroll
    for (int i = 0; i < 4; ++i)
#pragma unroll
      for (int j = 0; j < 4; ++j)
        acc[i][j] = __builtin_amdgcn_mfma_f32_16x16x32_bf16(af[i], bf[j], acc[i][j], 0, 0, 0);
    __syncthreads();
  }
  const int lrow = (lane >> 4) * 4;
#pragma unroll
  for (int i = 0; i < 4; ++i) {
    const int pbase = p0 + wm * 64 + i * 16 + lrow;
#pragma unroll
    for (int j = 0; j < 4; ++j) {
      const int r = r0 + wn * 64 + j * 16 + lr;
      const int t = r >> 5, o = r & 31;
      float4 v = {acc[i][j][0], acc[i][j][1], acc[i][j][2], acc[i][j][3]};
      *(float4*)&out[((size_t)o * NT + t) * NP + pbase] = v;
    }
  }
}

// ---------------------------------------------------------------- launch
extern "C" void kernel_launch(void* const* d_in, const int* in_sizes, int n_in,
                              void* d_out, int out_size, void* d_ws, size_t ws_size,
                              hipStream_t stream) {
  const float* x   = (const float*)d_in[0];
  const float* wr  = (const float*)d_in[1];
  const float* wi  = (const float*)d_in[2];
  const float* leg = (const float*)d_in[3];
  const float* wg  = (const float*)d_in[4];
  float* out = (float*)d_out;

  unsigned short* tw1t = (unsigned short*)d_ws;     // 256*512   = 131072
  unsigned short* vt   = tw1t + 131072;             // 512*256   = 131072
  unsigned short* xb   = vt + 131072;               // 8192*512  = 4194304
  float* fwr = (float*)(xb + 4194304);              // 128*256*32 = 1048576 floats
  float* fwi = fwr + 1048576;
  float* flr = fwi + 1048576;                       // 128*128*32 = 524288
  float* fli = flr + 524288;
  float* ya  = fli + 524288;
  float* yb  = ya + 524288;
  float* gp  = yb + 524288;                         // 4 * 256*8192 = 8388608
                                                    // total ~59 MB

  hipLaunchKernelGGL(kp_prep, dim3(2560), dim3(256), 0, stream, x, tw1t, vt, xb);
  hipLaunchKernelGGL(k1_mfma, dim3(64, 4), dim3(256), 0, stream, xb, tw1t, wg, fwr, fwi);
  hipLaunchKernelGGL(k2_flm, dim3(128, 32), dim3(256), 0, stream, leg, fwr, fwi, flr, fli);
  hipLaunchKernelGGL(k3_mix, dim3(128, 32), dim3(256), 0, stream, flr, fli, wr, wi, ya, yb);
  hipLaunchKernelGGL(k4_G, dim3(128, 32), dim3(256), 0, stream, leg, ya, yb, gp);
  hipLaunchKernelGGL(k5_mfma, dim3(4, 64), dim3(256), 0, stream, gp, vt, out);
}